// Round 15
// baseline (394.951 us; speedup 1.0000x reference)
//
#include <hip/hip_runtime.h>
#include <math.h>

namespace {

constexpr int kC  = 200;   // channels
constexpr int kD  = 800;   // 4*C
constexpr int kS  = 25;    // seq
constexpr int kH  = 32;    // hidden
constexpr int kNC = 16;    // classes
constexpr int kR  = 8;     // rows per block (4 waves x 2 rows, wave-autonomous)
constexpr int kRW = 800;   // LDS row stride in words (XOR swizzle for banks)

typedef float vfloat4 __attribute__((ext_vector_type(4)));  // native clang vec

// word offset of chunk m (4 floats) within a row: XOR-swizzle bank spreading.
__device__ __forceinline__ int woff(int m) { return (m << 2) ^ ((m & 0x38) >> 1); }

__device__ __forceinline__ float4 ld4(const float* p) { return *(const float4*)p; }
__device__ __forceinline__ float4 ld4nt(const float* p) {
    vfloat4 v = __builtin_nontemporal_load((const vfloat4*)p);
    return make_float4(v.x, v.y, v.z, v.w);
}
__device__ __forceinline__ void   st4(float* p, float4 v) { *(float4*)p = v; }
__device__ __forceinline__ float  hsum4(float4 v) { return (v.x + v.y) + (v.z + v.w); }

__device__ __forceinline__ float4 f4fma(float s, float4 w, float4 a) {
    a.x = fmaf(s, w.x, a.x); a.y = fmaf(s, w.y, a.y);
    a.z = fmaf(s, w.z, a.z); a.w = fmaf(s, w.w, a.w);
    return a;
}
__device__ __forceinline__ float4 f4add(float4 a, float4 b) {
    return make_float4(a.x + b.x, a.y + b.y, a.z + b.z, a.w + b.w);
}
__device__ __forceinline__ float4 shfl4_xor(float4 v, int m) {
    return make_float4(__shfl_xor(v.x, m, 64), __shfl_xor(v.y, m, 64),
                       __shfl_xor(v.z, m, 64), __shfl_xor(v.w, m, 64));
}
__device__ __forceinline__ float4 gelu4(float4 u) {
    const float k = 0.70710678118654752440f;
    return make_float4(0.5f * u.x * (1.0f + erff(u.x * k)),
                       0.5f * u.y * (1.0f + erff(u.y * k)),
                       0.5f * u.z * (1.0f + erff(u.z * k)),
                       0.5f * u.w * (1.0f + erff(u.w * k)));
}

// Intra-wave LDS fence: wave-local RAW through LDS only needs lgkmcnt(0).
__device__ __forceinline__ void wfence() {
    asm volatile("s_waitcnt lgkmcnt(0)" ::: "memory");
}

// ---------------- phase 1: x -> h workspace (pure streaming) ----------------
__global__ __launch_bounds__(256)
void featurize_kernel(const float* __restrict__ x, float* __restrict__ hws, int Btot)
{
    const int gid = blockIdx.x * 256 + threadIdx.x;
    if (gid >= Btot * 50) return;
    const int row = gid / 50;
    const int cq  = gid - row * 50;

    const float* xp = x + (size_t)row * (kS * kC) + cq * 4;
    float4 v = ld4nt(xp);
    float4 mn = v, mx = v, sm = v;
    #pragma unroll
    for (int s = 1; s < kS - 1; ++s) {
        float4 u = ld4nt(xp + s * kC);
        mn.x = fminf(mn.x, u.x); mx.x = fmaxf(mx.x, u.x); sm.x += u.x;
        mn.y = fminf(mn.y, u.y); mx.y = fmaxf(mx.y, u.y); sm.y += u.y;
        mn.z = fminf(mn.z, u.z); mx.z = fmaxf(mx.z, u.z); sm.z += u.z;
        mn.w = fminf(mn.w, u.w); mx.w = fmaxf(mx.w, u.w); sm.w += u.w;
    }
    float4 last = ld4nt(xp + (kS - 1) * kC);
    const float i24 = 1.0f / 24.0f;
    float* hp = hws + (size_t)row * kD + 16 * cq;   // plain row-major h
    st4(hp + 0,  make_float4(mn.x, sm.x * i24, last.x, mx.x));
    st4(hp + 4,  make_float4(mn.y, sm.y * i24, last.y, mx.y));
    st4(hp + 8,  make_float4(mn.z, sm.z * i24, last.z, mx.z));
    st4(hp + 12, make_float4(mn.w, sm.w * i24, last.w, mx.w));
}

// LayerNorm of one 800-elem LDS row by one full wave (lane j owns chunks
// j, j+64, j+128, and lanes 0..7 own 192+j). Two-pass, writes y to yrow.
__device__ __forceinline__ void ln_row(const float* hrow, float* yrow,
                                       const float* __restrict__ g,
                                       const float* __restrict__ bb, int j)
{
    const bool tail = (j < 8);
    float4 v0 = ld4(&hrow[woff(j)]);
    float4 v1 = ld4(&hrow[woff(j + 64)]);
    float4 v2 = ld4(&hrow[woff(j + 128)]);
    float4 v3 = make_float4(0.f, 0.f, 0.f, 0.f);
    if (tail) v3 = ld4(&hrow[woff(192 + j)]);

    float sm = hsum4(v0) + hsum4(v1) + hsum4(v2) + hsum4(v3);
    #pragma unroll
    for (int mk = 32; mk >= 1; mk >>= 1) sm += __shfl_xor(sm, mk, 64);
    const float mean = sm * (1.0f / 800.0f);

    float ssq = 0.f;
    { float a=v0.x-mean,b=v0.y-mean,c=v0.z-mean,d=v0.w-mean; ssq += a*a+b*b+c*c+d*d; }
    { float a=v1.x-mean,b=v1.y-mean,c=v1.z-mean,d=v1.w-mean; ssq += a*a+b*b+c*c+d*d; }
    { float a=v2.x-mean,b=v2.y-mean,c=v2.z-mean,d=v2.w-mean; ssq += a*a+b*b+c*c+d*d; }
    if (tail) { float a=v3.x-mean,b=v3.y-mean,c=v3.z-mean,d=v3.w-mean; ssq += a*a+b*b+c*c+d*d; }
    #pragma unroll
    for (int mk = 32; mk >= 1; mk >>= 1) ssq += __shfl_xor(ssq, mk, 64);
    const float rstd = rsqrtf(ssq * (1.0f / 800.0f) + 1e-5f);

    auto stc = [&](int m, float4 v) {
        float4 g4 = ld4(&g[4 * m]);
        float4 b4 = ld4(&bb[4 * m]);
        float4 y;
        y.x = (v.x - mean) * rstd * g4.x + b4.x;
        y.y = (v.y - mean) * rstd * g4.y + b4.y;
        y.z = (v.z - mean) * rstd * g4.z + b4.z;
        y.w = (v.w - mean) * rstd * g4.w + b4.w;
        st4(&yrow[woff(m)], y);
    };
    stc(j, v0); stc(j + 64, v1); stc(j + 128, v2);
    if (tail) stc(192 + j, v3);
}

// h += sppcf(y); wave-local (lane j owns same chunks as ln_row).
__device__ __forceinline__ void sppcf_add(const float* yrow, float* hrow, int j)
{
    auto one = [&](int m) {
        const int kk = (m <= 196) ? m : m - 4;          // f2 tail -> p16[m-4]
        float4 q0 = ld4(&yrow[woff(kk)]);
        float4 q1 = ld4(&yrow[woff(kk + 1)]);
        float4 q2 = ld4(&yrow[woff(kk + 2)]);
        float4 q3 = ld4(&yrow[woff(kk + 3)]);
        float4 y4 = (m <= 196) ? q0 : ld4(&yrow[woff(m)]);
        const float s16 = hsum4(q0) + hsum4(q1) + hsum4(q2) + hsum4(q3);
        float4 h4 = ld4(&hrow[woff(m)]);
        h4.x += (y4.x + y4.y) * 0.5f;
        h4.y += (y4.x + y4.y + y4.z + y4.w) * 0.25f;
        h4.z += (y4.z + y4.w) * 0.5f;
        h4.w += s16 * (1.0f / 16.0f);
        st4(&hrow[woff(m)], h4);
    };
    one(j); one(j + 64); one(j + 128);
    if (j < 8) one(192 + j);
}

// ---------------- phase 2: transformer layers + head (WAVE-AUTONOMOUS) ----
// 4 waves x 2 rows; each wave runs the full per-row pipeline with ZERO block
// barriers (wfence only). mm1 is wave-local via lane split (r|kseg|hq) with
// shfl_xor K-reduction; mm2 is wave-local chunk-ownership. Weights are read
// once per WAVE (L1/L2-hot across waves).
template<bool FROMWS>
__global__ __launch_bounds__(256)
void essp_main(const float* __restrict__ src,
               const float* __restrict__ lnA_g, const float* __restrict__ lnA_b,
               const float* __restrict__ lnB_g, const float* __restrict__ lnB_b,
               const float* __restrict__ w1, const float* __restrict__ b1,
               const float* __restrict__ w2, const float* __restrict__ b2,
               const float* __restrict__ fc_w, const float* __restrict__ fc_b,
               float* __restrict__ out, int Btot)
{
    __shared__ float hs[kR * kRW];   // residual h (8 rows, swizzled chunks)
    __shared__ float zb[kR * kRW];   // y/z buffer; pooled (wave-local rows)
    __shared__ float vb[kR * kH];    // gelu outputs (wave-local rows)

    const int t   = threadIdx.x;
    const int w   = t >> 6;          // wave id; wave owns rows w and w+4
    const int j   = t & 63;          // lane
    const int b0  = blockIdx.x * kR;
    const int lr0 = w, lr1 = w + 4;

    // mm1 lane split: r (which of the wave's 2 rows), kseg (K quarter), hq
    const int r_    = j >> 5;
    const int kseg  = (j >> 3) & 3;
    const int hq    = j & 7;
    const int lrm   = w + 4 * r_;    // mm1 row for this lane

    // ---- load/compute h for this wave's 2 rows ----
    #pragma unroll
    for (int rr = 0; rr < 2; ++rr) {
        const int lr  = w + 4 * rr;
        const int row = b0 + lr;
        if constexpr (FROMWS) {
            if (row < Btot) {
                const float* hg = src + (size_t)row * kD;
                float* hr = &hs[lr * kRW];
                st4(&hr[woff(j)],       ld4(&hg[4 * j]));
                st4(&hr[woff(j + 64)],  ld4(&hg[4 * (j + 64)]));
                st4(&hr[woff(j + 128)], ld4(&hg[4 * (j + 128)]));
                if (j < 8) st4(&hr[woff(192 + j)], ld4(&hg[4 * (192 + j)]));
            }
        } else {
            if (j < 50 && row < Btot) {
                const float* xp = src + (size_t)row * (kS * kC) + j * 4;
                float4 v = ld4nt(xp);
                float4 mn = v, mx = v, sm = v;
                #pragma unroll
                for (int s = 1; s < kS - 1; ++s) {
                    float4 u = ld4nt(xp + s * kC);
                    mn.x = fminf(mn.x, u.x); mx.x = fmaxf(mx.x, u.x); sm.x += u.x;
                    mn.y = fminf(mn.y, u.y); mx.y = fmaxf(mx.y, u.y); sm.y += u.y;
                    mn.z = fminf(mn.z, u.z); mx.z = fmaxf(mx.z, u.z); sm.z += u.z;
                    mn.w = fminf(mn.w, u.w); mx.w = fmaxf(mx.w, u.w); sm.w += u.w;
                }
                float4 last = ld4nt(xp + (kS - 1) * kC);
                const float i24 = 1.0f / 24.0f;
                float* hr = &hs[lr * kRW];
                st4(&hr[woff(4 * j + 0)], make_float4(mn.x, sm.x * i24, last.x, mx.x));
                st4(&hr[woff(4 * j + 1)], make_float4(mn.y, sm.y * i24, last.y, mx.y));
                st4(&hr[woff(4 * j + 2)], make_float4(mn.z, sm.z * i24, last.z, mx.z));
                st4(&hr[woff(4 * j + 3)], make_float4(mn.w, sm.w * i24, last.w, mx.w));
            }
        }
    }
    wfence();

    for (int layer = 0; layer < 2; ++layer) {
        const float* gA  = lnA_g + layer * kD;
        const float* bAv = lnA_b + layer * kD;
        const float* gB  = lnB_g + layer * kD;
        const float* bBv = lnB_b + layer * kD;
        const float* w1p = w1 + layer * kD * kH;
        const float* b1p = b1 + layer * kH;
        const float* w2p = w2 + layer * kH * kD;
        const float* b2p = b2 + layer * kD;

        // ---- row-local chain: wave does its 2 rows ----
        ln_row(&hs[lr0 * kRW], &zb[lr0 * kRW], gA, bAv, j);
        ln_row(&hs[lr1 * kRW], &zb[lr1 * kRW], gA, bAv, j);
        wfence();
        sppcf_add(&zb[lr0 * kRW], &hs[lr0 * kRW], j);
        sppcf_add(&zb[lr1 * kRW], &hs[lr1 * kRW], j);
        wfence();
        ln_row(&hs[lr0 * kRW], &zb[lr0 * kRW], gB, bBv, j);
        ln_row(&hs[lr1 * kRW], &zb[lr1 * kRW], gB, bBv, j);
        wfence();                               // z ready (wave-local)

        // ---- mm1 (wave-local): u[lrm][4hq..4hq+3] over K-quarter kseg ----
        {
            const float* zrow = &zb[lrm * kRW];
            float4 uacc = make_float4(0.f, 0.f, 0.f, 0.f);
            #pragma unroll 5
            for (int c = 0; c < 50; ++c) {
                const int m = kseg * 50 + c;
                float4 z4 = ld4(&zrow[woff(m)]);
                float4 w0 = ld4(&w1p[(4 * m + 0) * kH + 4 * hq]);
                float4 w1q = ld4(&w1p[(4 * m + 1) * kH + 4 * hq]);
                float4 w2q = ld4(&w1p[(4 * m + 2) * kH + 4 * hq]);
                float4 w3q = ld4(&w1p[(4 * m + 3) * kH + 4 * hq]);
                uacc = f4fma(z4.x, w0,  uacc);
                uacc = f4fma(z4.y, w1q, uacc);
                uacc = f4fma(z4.z, w2q, uacc);
                uacc = f4fma(z4.w, w3q, uacc);
            }
            // reduce over the 4 ksegs (lane bits 3,4)
            uacc = f4add(uacc, shfl4_xor(uacc, 8));
            uacc = f4add(uacc, shfl4_xor(uacc, 16));
            float4 b1q = ld4(&b1p[4 * hq]);
            float4 v4  = gelu4(f4add(uacc, b1q));
            if (kseg == 0) st4(&vb[lrm * kH + 4 * hq], v4);
        }
        wfence();                               // vb ready (wave-local)

        // ---- mm2 (wave-local): lane j owns chunks {j, j+64, j+128, tail} ----
        {
            auto mm2_chunk = [&](int m) {
                float4 a0 = make_float4(0.f, 0.f, 0.f, 0.f), a1 = a0;
                #pragma unroll
                for (int hc = 0; hc < 8; ++hc) {
                    float4 wq0 = ld4(&w2p[(4 * hc + 0) * kD + 4 * m]);
                    float4 wq1 = ld4(&w2p[(4 * hc + 1) * kD + 4 * m]);
                    float4 wq2 = ld4(&w2p[(4 * hc + 2) * kD + 4 * m]);
                    float4 wq3 = ld4(&w2p[(4 * hc + 3) * kD + 4 * m]);
                    float4 v0 = ld4(&vb[lr0 * kH + 4 * hc]);   // broadcast
                    a0 = f4fma(v0.x, wq0, a0); a0 = f4fma(v0.y, wq1, a0);
                    a0 = f4fma(v0.z, wq2, a0); a0 = f4fma(v0.w, wq3, a0);
                    float4 v1 = ld4(&vb[lr1 * kH + 4 * hc]);   // broadcast
                    a1 = f4fma(v1.x, wq0, a1); a1 = f4fma(v1.y, wq1, a1);
                    a1 = f4fma(v1.z, wq2, a1); a1 = f4fma(v1.w, wq3, a1);
                }
                float4 bq = ld4(&b2p[4 * m]);
                const int wo = woff(m);
                {
                    float4 h4 = ld4(&hs[lr0 * kRW + wo]);
                    h4.x += a0.x + bq.x; h4.y += a0.y + bq.y;
                    h4.z += a0.z + bq.z; h4.w += a0.w + bq.w;
                    st4(&hs[lr0 * kRW + wo], h4);
                }
                {
                    float4 h4 = ld4(&hs[lr1 * kRW + wo]);
                    h4.x += a1.x + bq.x; h4.y += a1.y + bq.y;
                    h4.z += a1.z + bq.z; h4.w += a1.w + bq.w;
                    st4(&hs[lr1 * kRW + wo], h4);
                }
            };
            mm2_chunk(j);
            mm2_chunk(j + 64);
            mm2_chunk(j + 128);
            if (j < 8) mm2_chunk(192 + j);
        }
        wfence();                               // h ready for next layer
    }

    // ---- pooled = mean4(h) (wave-local, 2 rows, into dead zb, plain layout) ----
    #pragma unroll
    for (int rr = 0; rr < 2; ++rr) {
        const int lr = w + 4 * rr;
        const float* hr = &hs[lr * kRW];
        float* pr = &zb[lr * kRW];
        pr[j]       = hsum4(ld4(&hr[woff(j)]))       * 0.25f;
        pr[j + 64]  = hsum4(ld4(&hr[woff(j + 64)]))  * 0.25f;
        pr[j + 128] = hsum4(ld4(&hr[woff(j + 128)])) * 0.25f;
        if (j < 8) pr[192 + j] = hsum4(ld4(&hr[woff(192 + j)])) * 0.25f;
    }
    wfence();

    // ---- out = pooled @ fc_w + fc_b (wave-local, 2 rows) ----
    #pragma unroll
    for (int rr = 0; rr < 2; ++rr) {
        const int lr  = w + 4 * rr;
        const int row = b0 + lr;
        const int n = j & 15, sg = j >> 4;
        const float* pr = &zb[lr * kRW + sg * 50];
        const float* fw = fc_w + (size_t)(sg * 50) * kNC + n;
        float acc = 0.f;
        #pragma unroll 10
        for (int i = 0; i < 50; ++i) acc += pr[i] * fw[i * kNC];
        acc += __shfl_xor(acc, 16, 64);
        acc += __shfl_xor(acc, 32, 64);
        if (j < kNC && row < Btot)
            out[(size_t)row * kNC + j] = acc + fc_b[j];
    }
}

} // namespace

extern "C" void kernel_launch(void* const* d_in, const int* in_sizes, int n_in,
                              void* d_out, int out_size, void* d_ws, size_t ws_size,
                              hipStream_t stream) {
    const float* x     = (const float*)d_in[0];
    const float* lnA_g = (const float*)d_in[1];
    const float* lnA_b = (const float*)d_in[2];
    const float* lnB_g = (const float*)d_in[3];
    const float* lnB_b = (const float*)d_in[4];
    const float* w1    = (const float*)d_in[5];
    const float* b1    = (const float*)d_in[6];
    const float* w2    = (const float*)d_in[7];
    const float* b2    = (const float*)d_in[8];
    const float* fc_w  = (const float*)d_in[9];
    const float* fc_b  = (const float*)d_in[10];
    float* out = (float*)d_out;

    const int Btot   = in_sizes[0] / (kS * kC);
    const int blocks = (Btot + kR - 1) / kR;
    const size_t hbytes = (size_t)Btot * kD * sizeof(float);

    if (ws_size >= hbytes) {
        float* hws = (float*)d_ws;
        const int fblocks = (Btot * 50 + 255) / 256;
        hipLaunchKernelGGL(featurize_kernel, dim3(fblocks), dim3(256), 0, stream,
                           x, hws, Btot);
        hipLaunchKernelGGL((essp_main<true>), dim3(blocks), dim3(256), 0, stream,
                           hws, lnA_g, lnA_b, lnB_g, lnB_b, w1, b1, w2, b2,
                           fc_w, fc_b, out, Btot);
    } else {
        hipLaunchKernelGGL((essp_main<false>), dim3(blocks), dim3(256), 0, stream,
                           x, lnA_g, lnA_b, lnB_g, lnB_b, w1, b1, w2, b2,
                           fc_w, fc_b, out, Btot);
    }
}

// Round 16
// 189.914 us; speedup vs baseline: 2.0796x; 2.0796x over previous
//
#include <hip/hip_runtime.h>
#include <math.h>

namespace {

constexpr int kC  = 200;   // channels
constexpr int kD  = 800;   // 4*C
constexpr int kS  = 25;    // seq
constexpr int kH  = 32;    // hidden
constexpr int kNC = 16;    // classes
constexpr int kR  = 8;     // rows per block (each of 4 waves owns 2 rows)
constexpr int kRW = 800;   // LDS row stride in words (no pad; XOR swizzle instead)

typedef float vfloat4 __attribute__((ext_vector_type(4)));  // native clang vec

// word offset of chunk m (4 floats) within a row: XOR-swizzle bank spreading.
__device__ __forceinline__ int woff(int m) { return (m << 2) ^ ((m & 0x38) >> 1); }

__device__ __forceinline__ float4 ld4(const float* p) { return *(const float4*)p; }
__device__ __forceinline__ float4 ld4nt(const float* p) {
    vfloat4 v = __builtin_nontemporal_load((const vfloat4*)p);
    return make_float4(v.x, v.y, v.z, v.w);
}
__device__ __forceinline__ void   st4(float* p, float4 v) { *(float4*)p = v; }
__device__ __forceinline__ float  hsum4(float4 v) { return (v.x + v.y) + (v.z + v.w); }

__device__ __forceinline__ float4 f4fma(float s, float4 w, float4 a) {
    a.x = fmaf(s, w.x, a.x); a.y = fmaf(s, w.y, a.y);
    a.z = fmaf(s, w.z, a.z); a.w = fmaf(s, w.w, a.w);
    return a;
}

// Intra-wave LDS fence: wave-local RAW through LDS only needs lgkmcnt(0).
__device__ __forceinline__ void wfence() {
    asm volatile("s_waitcnt lgkmcnt(0)" ::: "memory");
}

// ---------------- phase 1: x -> h workspace (pure streaming) ----------------
__global__ __launch_bounds__(256)
void featurize_kernel(const float* __restrict__ x, float* __restrict__ hws, int Btot)
{
    const int gid = blockIdx.x * 256 + threadIdx.x;
    if (gid >= Btot * 50) return;
    const int row = gid / 50;
    const int cq  = gid - row * 50;

    const float* xp = x + (size_t)row * (kS * kC) + cq * 4;
    float4 v = ld4nt(xp);
    float4 mn = v, mx = v, sm = v;
    #pragma unroll
    for (int s = 1; s < kS - 1; ++s) {
        float4 u = ld4nt(xp + s * kC);
        mn.x = fminf(mn.x, u.x); mx.x = fmaxf(mx.x, u.x); sm.x += u.x;
        mn.y = fminf(mn.y, u.y); mx.y = fmaxf(mx.y, u.y); sm.y += u.y;
        mn.z = fminf(mn.z, u.z); mx.z = fmaxf(mx.z, u.z); sm.z += u.z;
        mn.w = fminf(mn.w, u.w); mx.w = fmaxf(mx.w, u.w); sm.w += u.w;
    }
    float4 last = ld4nt(xp + (kS - 1) * kC);
    const float i24 = 1.0f / 24.0f;
    float* hp = hws + (size_t)row * kD + 16 * cq;   // plain row-major h
    st4(hp + 0,  make_float4(mn.x, sm.x * i24, last.x, mx.x));
    st4(hp + 4,  make_float4(mn.y, sm.y * i24, last.y, mx.y));
    st4(hp + 8,  make_float4(mn.z, sm.z * i24, last.z, mx.z));
    st4(hp + 12, make_float4(mn.w, sm.w * i24, last.w, mx.w));
}

// LayerNorm of one 800-elem LDS row by one full wave (lane j owns chunks
// j, j+64, j+128, and lanes 0..7 own 192+j). Two-pass, writes y to yrow.
__device__ __forceinline__ void ln_row(const float* hrow, float* yrow,
                                       const float* __restrict__ g,
                                       const float* __restrict__ bb, int j)
{
    const bool tail = (j < 8);
    float4 v0 = ld4(&hrow[woff(j)]);
    float4 v1 = ld4(&hrow[woff(j + 64)]);
    float4 v2 = ld4(&hrow[woff(j + 128)]);
    float4 v3 = make_float4(0.f, 0.f, 0.f, 0.f);
    if (tail) v3 = ld4(&hrow[woff(192 + j)]);

    float sm = hsum4(v0) + hsum4(v1) + hsum4(v2) + hsum4(v3);
    #pragma unroll
    for (int mk = 32; mk >= 1; mk >>= 1) sm += __shfl_xor(sm, mk, 64);
    const float mean = sm * (1.0f / 800.0f);

    float ssq = 0.f;
    { float a=v0.x-mean,b=v0.y-mean,c=v0.z-mean,d=v0.w-mean; ssq += a*a+b*b+c*c+d*d; }
    { float a=v1.x-mean,b=v1.y-mean,c=v1.z-mean,d=v1.w-mean; ssq += a*a+b*b+c*c+d*d; }
    { float a=v2.x-mean,b=v2.y-mean,c=v2.z-mean,d=v2.w-mean; ssq += a*a+b*b+c*c+d*d; }
    if (tail) { float a=v3.x-mean,b=v3.y-mean,c=v3.z-mean,d=v3.w-mean; ssq += a*a+b*b+c*c+d*d; }
    #pragma unroll
    for (int mk = 32; mk >= 1; mk >>= 1) ssq += __shfl_xor(ssq, mk, 64);
    const float rstd = rsqrtf(ssq * (1.0f / 800.0f) + 1e-5f);

    auto stc = [&](int m, float4 v) {
        float4 g4 = ld4(&g[4 * m]);
        float4 b4 = ld4(&bb[4 * m]);
        float4 y;
        y.x = (v.x - mean) * rstd * g4.x + b4.x;
        y.y = (v.y - mean) * rstd * g4.y + b4.y;
        y.z = (v.z - mean) * rstd * g4.z + b4.z;
        y.w = (v.w - mean) * rstd * g4.w + b4.w;
        st4(&yrow[woff(m)], y);
    };
    stc(j, v0); stc(j + 64, v1); stc(j + 128, v2);
    if (tail) stc(192 + j, v3);
}

// h += sppcf(y); wave-local (lane j owns same chunks as ln_row).
__device__ __forceinline__ void sppcf_add(const float* yrow, float* hrow, int j)
{
    auto one = [&](int m) {
        const int kk = (m <= 196) ? m : m - 4;          // f2 tail -> p16[m-4]
        float4 q0 = ld4(&yrow[woff(kk)]);
        float4 q1 = ld4(&yrow[woff(kk + 1)]);
        float4 q2 = ld4(&yrow[woff(kk + 2)]);
        float4 q3 = ld4(&yrow[woff(kk + 3)]);
        float4 y4 = (m <= 196) ? q0 : ld4(&yrow[woff(m)]);
        const float s16 = hsum4(q0) + hsum4(q1) + hsum4(q2) + hsum4(q3);
        float4 h4 = ld4(&hrow[woff(m)]);
        h4.x += (y4.x + y4.y) * 0.5f;
        h4.y += (y4.x + y4.y + y4.z + y4.w) * 0.25f;
        h4.z += (y4.z + y4.w) * 0.5f;
        h4.w += s16 * (1.0f / 16.0f);
        st4(&hrow[woff(m)], h4);
    };
    one(j); one(j + 64); one(j + 128);
    if (j < 8) one(192 + j);
}

// ---------------- phase 2: transformer layers + head ----------------
// FROMWS=true : src = h workspace (plain row-major, from featurize_kernel)
// FROMWS=false: src = x (fused fallback)
template<bool FROMWS>
__global__ __launch_bounds__(256)
void essp_main(const float* __restrict__ src,
               const float* __restrict__ lnA_g, const float* __restrict__ lnA_b,
               const float* __restrict__ lnB_g, const float* __restrict__ lnB_b,
               const float* __restrict__ w1, const float* __restrict__ b1,
               const float* __restrict__ w2, const float* __restrict__ b2,
               const float* __restrict__ fc_w, const float* __restrict__ fc_b,
               float* __restrict__ out, int Btot)
{
    __shared__ float hs[kR * kRW];   // residual state h (8 rows, swizzled chunks)
    __shared__ float zb[kR * kRW];   // y/z buffer; mm1 partials; pooled
    __shared__ float vb[kR * kH];    // gelu outputs

    const int t   = threadIdx.x;
    const int w   = t >> 6;          // wave id; wave owns rows w and w+4
    const int j   = t & 63;          // lane
    const int b0  = blockIdx.x * kR;

    // ---- load/compute h for this wave's 2 rows ----
    #pragma unroll
    for (int rr = 0; rr < 2; ++rr) {
        const int lr  = w + 4 * rr;          // local row
        const int row = b0 + lr;
        if constexpr (FROMWS) {
            if (row < Btot) {
                const float* hg = src + (size_t)row * kD;
                float* hr = &hs[lr * kRW];
                st4(&hr[woff(j)],       ld4(&hg[4 * j]));
                st4(&hr[woff(j + 64)],  ld4(&hg[4 * (j + 64)]));
                st4(&hr[woff(j + 128)], ld4(&hg[4 * (j + 128)]));
                if (j < 8) st4(&hr[woff(192 + j)], ld4(&hg[4 * (192 + j)]));
            }
        } else {
            if (j < 50 && row < Btot) {
                const float* xp = src + (size_t)row * (kS * kC) + j * 4;
                float4 v = ld4nt(xp);
                float4 mn = v, mx = v, sm = v;
                #pragma unroll
                for (int s = 1; s < kS - 1; ++s) {
                    float4 u = ld4nt(xp + s * kC);
                    mn.x = fminf(mn.x, u.x); mx.x = fmaxf(mx.x, u.x); sm.x += u.x;
                    mn.y = fminf(mn.y, u.y); mx.y = fmaxf(mx.y, u.y); sm.y += u.y;
                    mn.z = fminf(mn.z, u.z); mx.z = fmaxf(mx.z, u.z); sm.z += u.z;
                    mn.w = fminf(mn.w, u.w); mx.w = fmaxf(mx.w, u.w); sm.w += u.w;
                }
                float4 last = ld4nt(xp + (kS - 1) * kC);
                const float i24 = 1.0f / 24.0f;
                float* hr = &hs[lr * kRW];
                st4(&hr[woff(4 * j + 0)], make_float4(mn.x, sm.x * i24, last.x, mx.x));
                st4(&hr[woff(4 * j + 1)], make_float4(mn.y, sm.y * i24, last.y, mx.y));
                st4(&hr[woff(4 * j + 2)], make_float4(mn.z, sm.z * i24, last.z, mx.z));
                st4(&hr[woff(4 * j + 3)], make_float4(mn.w, sm.w * i24, last.w, mx.w));
            }
        }
    }
    wfence();

    for (int layer = 0; layer < 2; ++layer) {
        const float* gA  = lnA_g + layer * kD;
        const float* bAv = lnA_b + layer * kD;
        const float* gB  = lnB_g + layer * kD;
        const float* bBv = lnB_b + layer * kD;
        const float* w1p = w1 + layer * kD * kH;
        const float* b1p = b1 + layer * kH;
        const float* w2p = w2 + layer * kH * kD;
        const float* b2p = b2 + layer * kD;

        // ---- row-local chain: each wave does its 2 rows ----
        ln_row(&hs[w * kRW], &zb[w * kRW], gA, bAv, j);
        ln_row(&hs[(w + 4) * kRW], &zb[(w + 4) * kRW], gA, bAv, j);
        wfence();
        sppcf_add(&zb[w * kRW], &hs[w * kRW], j);
        sppcf_add(&zb[(w + 4) * kRW], &hs[(w + 4) * kRW], j);
        wfence();
        ln_row(&hs[w * kRW], &zb[w * kRW], gB, bBv, j);
        ln_row(&hs[(w + 4) * kRW], &zb[(w + 4) * kRW], gB, bBv, j);
        __syncthreads();                       // mm1 reads all rows' z

        // ---- mm1: u = z @ w1, 8-row register amortization ----
        // thread (dg<25, cg<8): d-range [32dg,32dg+32), h-quad 4cg..4cg+3
        float4 acc[kR];
        const int dg = t >> 3, cg = t & 7;
        #pragma unroll
        for (int r = 0; r < kR; ++r) acc[r] = make_float4(0.f, 0.f, 0.f, 0.f);
        if (t < 200) {
            #pragma unroll
            for (int cc = 0; cc < 8; ++cc) {
                const int m = dg * 8 + cc, d0 = 4 * m;
                float4 wr0 = ld4(&w1p[(d0 + 0) * kH + 4 * cg]);
                float4 wr1 = ld4(&w1p[(d0 + 1) * kH + 4 * cg]);
                float4 wr2 = ld4(&w1p[(d0 + 2) * kH + 4 * cg]);
                float4 wr3 = ld4(&w1p[(d0 + 3) * kH + 4 * cg]);
                const int wo = woff(m);
                #pragma unroll
                for (int r = 0; r < kR; ++r) {
                    float4 z = ld4(&zb[r * kRW + wo]);
                    acc[r] = f4fma(z.x, wr0, acc[r]);
                    acc[r] = f4fma(z.y, wr1, acc[r]);
                    acc[r] = f4fma(z.z, wr2, acc[r]);
                    acc[r] = f4fma(z.w, wr3, acc[r]);
                }
            }
        }
        __syncthreads();                       // everyone done reading zb
        if (t < 200) {
            // partials into dead zb, swizzled: word(r,dg,h)=r*800+dg*32+(h^((dg&7)<<2))
            const int pb = dg * 32 + ((4 * cg) ^ ((dg & 7) << 2));
            #pragma unroll
            for (int r = 0; r < kR; ++r) st4(&zb[r * kRW + pb], acc[r]);
        }
        __syncthreads();

        // ---- reduce partials + bias + exact GELU -> vb (all 256 threads) ----
        {
            const int r = t >> 5, h = t & 31;
            float u = b1p[h];
            #pragma unroll
            for (int dq = 0; dq < 25; ++dq)
                u += zb[r * kRW + dq * 32 + (h ^ ((dq & 7) << 2))];
            vb[r * kH + h] = 0.5f * u * (1.0f + erff(u * 0.70710678118654752440f));
        }
        __syncthreads();

        // ---- mm2: h += v @ w2 + b2, chunk-stationary (w2 read ONCE per block) ----
        // thread t<200 owns chunk m=t (d = 4t..4t+3) for ALL 8 rows.
        if (t < 200) {
            float4 a2[kR];
            #pragma unroll
            for (int r = 0; r < kR; ++r) a2[r] = make_float4(0.f, 0.f, 0.f, 0.f);
            #pragma unroll
            for (int hc = 0; hc < 8; ++hc) {
                float4 wq0 = ld4(&w2p[(4*hc + 0) * kD + 4*t]);
                float4 wq1 = ld4(&w2p[(4*hc + 1) * kD + 4*t]);
                float4 wq2 = ld4(&w2p[(4*hc + 2) * kD + 4*t]);
                float4 wq3 = ld4(&w2p[(4*hc + 3) * kD + 4*t]);
                #pragma unroll
                for (int r = 0; r < kR; ++r) {
                    float4 vq = ld4(&vb[r * kH + 4*hc]);
                    a2[r] = f4fma(vq.x, wq0, a2[r]);
                    a2[r] = f4fma(vq.y, wq1, a2[r]);
                    a2[r] = f4fma(vq.z, wq2, a2[r]);
                    a2[r] = f4fma(vq.w, wq3, a2[r]);
                }
            }
            const float4 bq = ld4(&b2p[4*t]);
            const int wo = woff(t);
            #pragma unroll
            for (int r = 0; r < kR; ++r) {
                float4 h4 = ld4(&hs[r * kRW + wo]);
                h4.x += a2[r].x + bq.x; h4.y += a2[r].y + bq.y;
                h4.z += a2[r].z + bq.z; h4.w += a2[r].w + bq.w;
                st4(&hs[r * kRW + wo], h4);
            }
        }
        __syncthreads();                        // next phase reads hs cross-thread
    }

    // ---- pooled = mean4(h) (wave-local, 2 rows, into dead zb, plain layout) ----
    #pragma unroll
    for (int rr = 0; rr < 2; ++rr) {
        const int lr = w + 4 * rr;
        const float* hr = &hs[lr * kRW];
        float* pr = &zb[lr * kRW];
        pr[j]       = hsum4(ld4(&hr[woff(j)]))       * 0.25f;
        pr[j + 64]  = hsum4(ld4(&hr[woff(j + 64)]))  * 0.25f;
        pr[j + 128] = hsum4(ld4(&hr[woff(j + 128)])) * 0.25f;
        if (j < 8) pr[192 + j] = hsum4(ld4(&hr[woff(192 + j)])) * 0.25f;
    }
    wfence();

    // ---- out = pooled @ fc_w + fc_b (wave-local, 2 rows) ----
    #pragma unroll
    for (int rr = 0; rr < 2; ++rr) {
        const int lr  = w + 4 * rr;
        const int row = b0 + lr;
        const int n = j & 15, sg = j >> 4;
        const float* pr = &zb[lr * kRW + sg * 50];
        const float* fw = fc_w + (size_t)(sg * 50) * kNC + n;
        float acc = 0.f;
        #pragma unroll 10
        for (int i = 0; i < 50; ++i) acc += pr[i] * fw[i * kNC];
        acc += __shfl_xor(acc, 16, 64);
        acc += __shfl_xor(acc, 32, 64);
        if (j < kNC && row < Btot)
            out[(size_t)row * kNC + j] = acc + fc_b[j];
    }
}

} // namespace

extern "C" void kernel_launch(void* const* d_in, const int* in_sizes, int n_in,
                              void* d_out, int out_size, void* d_ws, size_t ws_size,
                              hipStream_t stream) {
    const float* x     = (const float*)d_in[0];
    const float* lnA_g = (const float*)d_in[1];
    const float* lnA_b = (const float*)d_in[2];
    const float* lnB_g = (const float*)d_in[3];
    const float* lnB_b = (const float*)d_in[4];
    const float* w1    = (const float*)d_in[5];
    const float* b1    = (const float*)d_in[6];
    const float* w2    = (const float*)d_in[7];
    const float* b2    = (const float*)d_in[8];
    const float* fc_w  = (const float*)d_in[9];
    const float* fc_b  = (const float*)d_in[10];
    float* out = (float*)d_out;

    const int Btot   = in_sizes[0] / (kS * kC);
    const int blocks = (Btot + kR - 1) / kR;
    const size_t hbytes = (size_t)Btot * kD * sizeof(float);

    if (ws_size >= hbytes) {
        float* hws = (float*)d_ws;
        const int fblocks = (Btot * 50 + 255) / 256;
        hipLaunchKernelGGL(featurize_kernel, dim3(fblocks), dim3(256), 0, stream,
                           x, hws, Btot);
        hipLaunchKernelGGL((essp_main<true>), dim3(blocks), dim3(256), 0, stream,
                           hws, lnA_g, lnA_b, lnB_g, lnB_b, w1, b1, w2, b2,
                           fc_w, fc_b, out, Btot);
    } else {
        hipLaunchKernelGGL((essp_main<false>), dim3(blocks), dim3(256), 0, stream,
                           x, lnA_g, lnA_b, lnB_g, lnB_b, w1, b1, w2, b2,
                           fc_w, fc_b, out, Btot);
    }
}